// Round 4
// baseline (383.070 us; speedup 1.0000x reference)
//
#include <hip/hip_runtime.h>

// ---------------------------------------------------------------------------
// Problem: h = relu(x + noise); BN1d(train, eps=0.8); z = hn @ W^T + b
// x: [8192, 4096] f32, W: [4096, 4096] f32, out: [8192, 4096] f32
// ---------------------------------------------------------------------------

#define B_ROWS 8192
#define C_CH   4096
#define N_OUT  4096

// ---------------------- compile-time noise table --------------------------
struct alignas(16) NoiseTable { float v[C_CH]; };

constexpr NoiseTable make_noise() {
    unsigned s = 123u;
    unsigned pool[C_CH] = {};
    for (int i = 0; i < C_CH; ++i) { s = 65539u * s + 1u; pool[i] = s; }
    int nxt = C_CH - 1;
    NoiseTable t{};
    for (int i = 0; i < C_CH; ++i) {
        nxt = (int)(pool[nxt] % (unsigned)C_CH);
        t.v[i] = (float)((double)pool[nxt] * 1e-9);
        s = 65539u * s + 1u;
        pool[nxt] = s;
    }
    return t;
}

__device__ constexpr NoiseTable NOISE = make_noise();

// ---------------------- helpers -------------------------------------------
__device__ __forceinline__ unsigned short f2bf(float f) {
    unsigned u = __builtin_bit_cast(unsigned, f);
    unsigned r = (u + 0x7FFFu + ((u >> 16) & 1u)) >> 16;   // RNE
    return (unsigned short)r;
}

typedef __attribute__((ext_vector_type(8))) short bf16x8;
typedef __attribute__((ext_vector_type(4))) float f32x4;

__device__ __forceinline__ void gload16(const void* g, void* l) {
    __builtin_amdgcn_global_load_lds(
        (const __attribute__((address_space(1))) void*)g,
        (__attribute__((address_space(3))) void*)l, 16, 0, 0);
}

#define BARRIER()  do { __builtin_amdgcn_s_barrier(); asm volatile("" ::: "memory"); } while (0)
#define LGKM0()    do { asm volatile("s_waitcnt lgkmcnt(0)" ::: "memory"); \
                        __builtin_amdgcn_sched_barrier(0); } while (0)

// ---------------------- 1) BN stats: per-block partial sums ----------------
__global__ __launch_bounds__(256) void stats_kernel(const float* __restrict__ x,
                                                    float* __restrict__ psum,
                                                    float* __restrict__ psumsq) {
    const int t = threadIdx.x;
    const int b = blockIdx.x;

    float4 nv[4];
    #pragma unroll
    for (int g = 0; g < 4; ++g)
        nv[g] = *reinterpret_cast<const float4*>(&NOISE.v[g * 1024 + 4 * t]);

    float4 s[4], q[4];
    #pragma unroll
    for (int g = 0; g < 4; ++g) { s[g] = make_float4(0,0,0,0); q[g] = make_float4(0,0,0,0); }

    const int row0 = b * 16;
    for (int r = 0; r < 16; ++r) {
        const float* xr = x + (size_t)(row0 + r) * C_CH;
        #pragma unroll
        for (int g = 0; g < 4; ++g) {
            float4 v = *reinterpret_cast<const float4*>(&xr[g * 1024 + 4 * t]);
            float h0 = fmaxf(v.x + nv[g].x, 0.f);
            float h1 = fmaxf(v.y + nv[g].y, 0.f);
            float h2 = fmaxf(v.z + nv[g].z, 0.f);
            float h3 = fmaxf(v.w + nv[g].w, 0.f);
            s[g].x += h0; s[g].y += h1; s[g].z += h2; s[g].w += h3;
            q[g].x += h0*h0; q[g].y += h1*h1; q[g].z += h2*h2; q[g].w += h3*h3;
        }
    }
    #pragma unroll
    for (int g = 0; g < 4; ++g) {
        *reinterpret_cast<float4*>(&psum  [(size_t)b * C_CH + g * 1024 + 4 * t]) = s[g];
        *reinterpret_cast<float4*>(&psumsq[(size_t)b * C_CH + g * 1024 + 4 * t]) = q[g];
    }
}

// ---------------------- 2) finalize: scale/shift per channel ---------------
__global__ __launch_bounds__(256) void finalize_kernel(const float* __restrict__ psum,
                                                       const float* __restrict__ psumsq,
                                                       const float* __restrict__ gamma,
                                                       const float* __restrict__ beta,
                                                       float* __restrict__ scale,
                                                       float* __restrict__ shift) {
    const int c = blockIdx.x * 256 + threadIdx.x;
    float s = 0.f, q = 0.f;
    for (int bk = 0; bk < 512; ++bk) {
        s += psum  [(size_t)bk * C_CH + c];
        q += psumsq[(size_t)bk * C_CH + c];
    }
    const float inv = 1.f / (float)B_ROWS;
    const float mean = s * inv;
    const float var  = fmaxf(q * inv - mean * mean, 0.f);
    const float sc   = gamma[c] / sqrtf(var + 0.8f);
    scale[c] = sc;
    shift[c] = beta[c] - mean * sc;
}

// ---------------------- 3) fused conversion: A (hn->bf16) + W (->bf16) -----
// blocks 0..2047: convA (16 iters/thread); blocks 2048..3071: convW (16 iters)
__global__ __launch_bounds__(256) void conv_kernel(const float* __restrict__ x,
                                                   const float* __restrict__ scale,
                                                   const float* __restrict__ shift,
                                                   unsigned short* __restrict__ Abf,
                                                   const float* __restrict__ W,
                                                   unsigned short* __restrict__ Wbf) {
    const int bid = blockIdx.x;
    if (bid < 2048) {
        const size_t total4 = (size_t)B_ROWS * C_CH / 4;
        for (size_t i = (size_t)bid * 256 + threadIdx.x; i < total4;
             i += (size_t)2048 * 256) {
            const size_t e = i * 4;
            const int c = (int)(e & (C_CH - 1));
            float4 v  = *reinterpret_cast<const float4*>(&x[e]);
            float4 nv = *reinterpret_cast<const float4*>(&NOISE.v[c]);
            float4 sc = *reinterpret_cast<const float4*>(&scale[c]);
            float4 sh = *reinterpret_cast<const float4*>(&shift[c]);
            ushort4 o;
            o.x = f2bf(fmaxf(v.x + nv.x, 0.f) * sc.x + sh.x);
            o.y = f2bf(fmaxf(v.y + nv.y, 0.f) * sc.y + sh.y);
            o.z = f2bf(fmaxf(v.z + nv.z, 0.f) * sc.z + sh.z);
            o.w = f2bf(fmaxf(v.w + nv.w, 0.f) * sc.w + sh.w);
            *reinterpret_cast<ushort4*>(&Abf[e]) = o;
        }
    } else {
        const int vb = bid - 2048;
        const size_t total4 = (size_t)N_OUT * C_CH / 4;
        for (size_t i = (size_t)vb * 256 + threadIdx.x; i < total4;
             i += (size_t)1024 * 256) {
            const size_t e = i * 4;
            float4 v = *reinterpret_cast<const float4*>(&W[e]);
            ushort4 o;
            o.x = f2bf(v.x); o.y = f2bf(v.y); o.z = f2bf(v.z); o.w = f2bf(v.w);
            *reinterpret_cast<ushort4*>(&Wbf[e]) = o;
        }
    }
}

// ---------------------- 5) GEMM 256x256x64, 8 waves, deep prefetch ---------
// LDS buffer (65536 B): A [256 rows][64 k] at +0 in 4 chunks of 64 rows
// (A0@0, A1@8192, A2@16384, A3@24576); B likewise at +32768 (B0..B3).
// T2 swizzle: within a row (8 x 16B slots) stored slot = slot ^ (row&7);
// global_load_lds writes linearly, SOURCE is pre-swizzled (both-sides rule).
//
// Prefetch ledger (per wave; chunks issued ALL at ph0 in order
// B0,B1,B2,B3,A0,A2,A1,A3 — maximum legal flight with 2 buffers):
//   ph0 entry: outstanding = 8 (this tile). Need oldest 6 -> vmcnt(2);
//              barrier (block-wide landing + dbuf reuse fence); issue 8 next.
//   ph2 entry: outstanding = 2 + 8. Need old A1,A3 -> vmcnt(8); barrier.
//   Flight: 4 phases for the 6, 6 phases for A1/A3. Never vmcnt(0) except tail.

template<int MH, int NH>
__device__ __forceinline__ void quad_mfma(bf16x8 (&af)[4][2], bf16x8 (&bf)[4][2],
                                          f32x4 (&acc)[8][4]) {
    #pragma unroll
    for (int s = 0; s < 2; ++s)
        #pragma unroll
        for (int m = 0; m < 4; ++m)
            #pragma unroll
            for (int n = 0; n < 2; ++n)
                acc[MH * 4 + m][NH * 2 + n] = __builtin_amdgcn_mfma_f32_16x16x32_bf16(
                    af[m][s], bf[NH * 2 + n][s], acc[MH * 4 + m][NH * 2 + n], 0, 0, 0);
}

template<bool STG>
__device__ __forceinline__ void tile_step(
    char* lds, const int bc, const int bn,
    const char*& pA0, const char*& pA1, const char*& pA2, const char*& pA3,
    const char*& pB0, const char*& pB1, const char*& pB2, const char*& pB3,
    const int dstw, const int aoff0, const int aoff1,
    const int boff0, const int boff1,
    f32x4 (&acc)[8][4]) {

    bf16x8 af[4][2], bf[4][2];

    // ======== phase 0: quad(m0-3, n0-1) ========
    asm volatile("s_waitcnt vmcnt(2)" ::: "memory");   // oldest 6 of this tile
    BARRIER();                       // block-wide landing + bn reuse fence
    __builtin_amdgcn_sched_barrier(0);
    if (STG) {                       // stage ALL of next tile now (max flight)
        gload16(pB0, lds + bn + 32768 + dstw);
        gload16(pB1, lds + bn + 40960 + dstw);
        gload16(pB2, lds + bn + 49152 + dstw);
        gload16(pB3, lds + bn + 57344 + dstw);
        gload16(pA0, lds + bn +     0 + dstw);
        gload16(pA2, lds + bn + 16384 + dstw);
        gload16(pA1, lds + bn +  8192 + dstw);
        gload16(pA3, lds + bn + 24576 + dstw);
        pA0 += 128; pA1 += 128; pA2 += 128; pA3 += 128;
        pB0 += 128; pB1 += 128; pB2 += 128; pB3 += 128;
    }
    #pragma unroll
    for (int m = 0; m < 4; ++m) {
        af[m][0] = *reinterpret_cast<const bf16x8*>(lds + bc + aoff0 + m * 2048);
        af[m][1] = *reinterpret_cast<const bf16x8*>(lds + bc + aoff1 + m * 2048);
    }
    #pragma unroll
    for (int n = 0; n < 2; ++n) {
        bf[n][0] = *reinterpret_cast<const bf16x8*>(lds + bc + boff0 + n * 2048);
        bf[n][1] = *reinterpret_cast<const bf16x8*>(lds + bc + boff1 + n * 2048);
    }
    LGKM0();
    __builtin_amdgcn_s_setprio(1);
    quad_mfma<0, 0>(af, bf, acc);
    __builtin_amdgcn_s_setprio(0);

    // ======== phase 1: quad(m0-3, n2-3) ========
    #pragma unroll
    for (int n = 2; n < 4; ++n) {
        bf[n][0] = *reinterpret_cast<const bf16x8*>(lds + bc + boff0 + n * 2048);
        bf[n][1] = *reinterpret_cast<const bf16x8*>(lds + bc + boff1 + n * 2048);
    }
    LGKM0();
    __builtin_amdgcn_s_setprio(1);
    quad_mfma<0, 1>(af, bf, acc);
    __builtin_amdgcn_s_setprio(0);

    // ======== phase 2: quad(m4-7, n2-3); needs old A1,A3 ========
    if (STG) asm volatile("s_waitcnt vmcnt(8)" ::: "memory");
    else     asm volatile("s_waitcnt vmcnt(0)" ::: "memory");
    BARRIER();
    __builtin_amdgcn_sched_barrier(0);
    #pragma unroll
    for (int m = 0; m < 4; ++m) {
        af[m][0] = *reinterpret_cast<const bf16x8*>(lds + bc + aoff0 + (m + 4) * 2048);
        af[m][1] = *reinterpret_cast<const bf16x8*>(lds + bc + aoff1 + (m + 4) * 2048);
    }
    LGKM0();
    __builtin_amdgcn_s_setprio(1);
    quad_mfma<1, 1>(af, bf, acc);
    __builtin_amdgcn_s_setprio(0);

    // ======== phase 3: quad(m4-7, n0-1); pure register phase ========
    __builtin_amdgcn_s_setprio(1);
    quad_mfma<1, 0>(af, bf, acc);
    __builtin_amdgcn_s_setprio(0);
}

__global__ __launch_bounds__(512, 2) void gemm256_kernel(
    const unsigned short* __restrict__ A, const unsigned short* __restrict__ B,
    const float* __restrict__ bias, float* __restrict__ C) {
    constexpr int K = C_CH, N = N_OUT;
    __shared__ alignas(128) char lds[131072];

    // XCD-bijective swizzle (nwg = 512, % 8 == 0)
    const int nwg = gridDim.x;
    const int cpx = nwg >> 3;
    int wg = blockIdx.x;
    wg = (wg & 7) * cpx + (wg >> 3);
    const int nbx = N >> 8;                 // 16
    const int bx = wg % nbx, by = wg / nbx;
    const int row0 = by << 8, col0 = bx << 8;

    const int t    = threadIdx.x;
    const int lane = t & 63;
    const int wid  = t >> 6;
    const int wm   = wid >> 2;              // 0..1
    const int wn   = wid & 3;               // 0..3
    const int l15  = lane & 15;
    const int lh   = lane >> 4;             // 0..3

    // staging source (pre-swizzled slot) and wave-uniform LDS dest
    const int sslot = (lane & 7) ^ (lane >> 3);
    const int dstw  = wid << 10;            // wid * 1024

    const char* pA0 = (const char*)A +
        ((size_t)(row0 + wid * 8 + (lane >> 3)) * K) * 2 + sslot * 16;
    const char* pA1 = pA0 + 1 * 64 * K * 2;
    const char* pA2 = pA0 + 2 * 64 * K * 2;
    const char* pA3 = pA0 + 3 * 64 * K * 2;
    const char* pB0 = (const char*)B +
        ((size_t)(col0 + wid * 8 + (lane >> 3)) * K) * 2 + sslot * 16;
    const char* pB1 = pB0 + 1 * 64 * K * 2;
    const char* pB2 = pB0 + 2 * 64 * K * 2;
    const char* pB3 = pB0 + 3 * 64 * K * 2;

    // fragment read offsets (T2 swizzle: slot ^ (row&7), row&7 == l15&7)
    const int x7 = l15 & 7;
    const int aoff0 = wm * 16384 + l15 * 128 + ((lh     ) ^ x7) * 16;
    const int aoff1 = wm * 16384 + l15 * 128 + ((lh +  4) ^ x7) * 16;
    const int boff0 = 32768 + wn * 8192 + l15 * 128 + ((lh    ) ^ x7) * 16;
    const int boff1 = 32768 + wn * 8192 + l15 * 128 + ((lh + 4) ^ x7) * 16;

    f32x4 acc[8][4];
    #pragma unroll
    for (int m = 0; m < 8; ++m)
        #pragma unroll
        for (int n = 0; n < 4; ++n)
            acc[m][n] = (f32x4){0.f, 0.f, 0.f, 0.f};

    // prologue: stage tile 0 into buf0 in the ledger's issue order
    gload16(pB0, lds + 32768 + dstw);
    gload16(pB1, lds + 40960 + dstw);
    gload16(pB2, lds + 49152 + dstw);
    gload16(pB3, lds + 57344 + dstw);
    gload16(pA0, lds +     0 + dstw);
    gload16(pA2, lds + 16384 + dstw);
    gload16(pA1, lds +  8192 + dstw);
    gload16(pA3, lds + 24576 + dstw);
    pA0 += 128; pA1 += 128; pA2 += 128; pA3 += 128;
    pB0 += 128; pB1 += 128; pB2 += 128; pB3 += 128;

    // 64 K-tiles: 31 double iterations + staged tile + tail tile
    #pragma unroll 1
    for (int it = 0; it < 31; ++it) {
        tile_step<true >(lds,     0, 65536, pA0, pA1, pA2, pA3, pB0, pB1, pB2, pB3,
                         dstw, aoff0, aoff1, boff0, boff1, acc);
        tile_step<true >(lds, 65536,     0, pA0, pA1, pA2, pA3, pB0, pB1, pB2, pB3,
                         dstw, aoff0, aoff1, boff0, boff1, acc);
    }
    tile_step<true >(lds,     0, 65536, pA0, pA1, pA2, pA3, pB0, pB1, pB2, pB3,
                     dstw, aoff0, aoff1, boff0, boff1, acc);
    tile_step<false>(lds, 65536,     0, pA0, pA1, pA2, pA3, pB0, pB1, pB2, pB3,
                     dstw, aoff0, aoff1, boff0, boff1, acc);

    // epilogue: C[row][col] = acc + bias[col]
    const int crow0 = row0 + wm * 128 + lh * 4;
    const int ccol0 = col0 + wn * 64 + l15;
    #pragma unroll
    for (int n = 0; n < 4; ++n) {
        const float bv = bias[ccol0 + n * 16];
        #pragma unroll
        for (int m = 0; m < 8; ++m) {
            const size_t base = (size_t)(crow0 + m * 16) * N + (ccol0 + n * 16);
            #pragma unroll
            for (int j = 0; j < 4; ++j)
                C[base + (size_t)j * N] = acc[m][n][j] + bv;
        }
    }
}

// ---------------------- launch --------------------------------------------
extern "C" void kernel_launch(void* const* d_in, const int* in_sizes, int n_in,
                              void* d_out, int out_size, void* d_ws, size_t ws_size,
                              hipStream_t stream) {
    const float* x     = (const float*)d_in[0];
    const float* gamma = (const float*)d_in[1];
    const float* beta  = (const float*)d_in[2];
    const float* W     = (const float*)d_in[3];
    const float* b     = (const float*)d_in[4];
    float* out = (float*)d_out;

    char* ws = (char*)d_ws;
    unsigned short* Abf = (unsigned short*)(ws);                       // 64 MiB
    unsigned short* Wbf = (unsigned short*)(ws + 67108864);            // 32 MiB
    float* psum   = (float*)(ws + 100663296);                          // 8 MiB
    float* psumsq = (float*)(ws + 100663296 + 8388608);                // 8 MiB
    float* scale  = (float*)(ws + 100663296 + 16777216);               // 16 KiB
    float* shift  = (float*)(ws + 100663296 + 16777216 + 16384);       // 16 KiB

    hipLaunchKernelGGL(stats_kernel,    dim3(512),  dim3(256), 0, stream, x, psum, psumsq);
    hipLaunchKernelGGL(finalize_kernel, dim3(16),   dim3(256), 0, stream,
                       psum, psumsq, gamma, beta, scale, shift);
    hipLaunchKernelGGL(conv_kernel,     dim3(3072), dim3(256), 0, stream,
                       x, scale, shift, Abf, W, Wbf);
    hipLaunchKernelGGL(gemm256_kernel,  dim3(512),  dim3(512), 0, stream,
                       Abf, Wbf, b, out);
}

// Round 5
// 378.077 us; speedup vs baseline: 1.0132x; 1.0132x over previous
//
#include <hip/hip_runtime.h>

// ---------------------------------------------------------------------------
// Problem: h = relu(x + noise); BN1d(train, eps=0.8); z = hn @ W^T + b
// x: [8192, 4096] f32, W: [4096, 4096] f32, out: [8192, 4096] f32
// ---------------------------------------------------------------------------

#define B_ROWS 8192
#define C_CH   4096
#define N_OUT  4096

// ---------------------- compile-time noise table --------------------------
struct alignas(16) NoiseTable { float v[C_CH]; };

constexpr NoiseTable make_noise() {
    unsigned s = 123u;
    unsigned pool[C_CH] = {};
    for (int i = 0; i < C_CH; ++i) { s = 65539u * s + 1u; pool[i] = s; }
    int nxt = C_CH - 1;
    NoiseTable t{};
    for (int i = 0; i < C_CH; ++i) {
        nxt = (int)(pool[nxt] % (unsigned)C_CH);
        t.v[i] = (float)((double)pool[nxt] * 1e-9);
        s = 65539u * s + 1u;
        pool[nxt] = s;
    }
    return t;
}

__device__ constexpr NoiseTable NOISE = make_noise();

// ---------------------- helpers -------------------------------------------
__device__ __forceinline__ unsigned short f2bf(float f) {
    unsigned u = __builtin_bit_cast(unsigned, f);
    unsigned r = (u + 0x7FFFu + ((u >> 16) & 1u)) >> 16;   // RNE
    return (unsigned short)r;
}

typedef __attribute__((ext_vector_type(8))) short bf16x8;
typedef __attribute__((ext_vector_type(4))) float f32x4;

__device__ __forceinline__ void gload16(const void* g, void* l) {
    __builtin_amdgcn_global_load_lds(
        (const __attribute__((address_space(1))) void*)g,
        (__attribute__((address_space(3))) void*)l, 16, 0, 0);
}

#define BARRIER()  do { __builtin_amdgcn_s_barrier(); asm volatile("" ::: "memory"); } while (0)
#define LGKM0()    do { asm volatile("s_waitcnt lgkmcnt(0)" ::: "memory"); \
                        __builtin_amdgcn_sched_barrier(0); } while (0)

// ---------------------- 1) BN stats: per-block partial sums ----------------
__global__ __launch_bounds__(256) void stats_kernel(const float* __restrict__ x,
                                                    float* __restrict__ psum,
                                                    float* __restrict__ psumsq) {
    const int t = threadIdx.x;
    const int b = blockIdx.x;

    float4 nv[4];
    #pragma unroll
    for (int g = 0; g < 4; ++g)
        nv[g] = *reinterpret_cast<const float4*>(&NOISE.v[g * 1024 + 4 * t]);

    float4 s[4], q[4];
    #pragma unroll
    for (int g = 0; g < 4; ++g) { s[g] = make_float4(0,0,0,0); q[g] = make_float4(0,0,0,0); }

    const int row0 = b * 16;
    for (int r = 0; r < 16; ++r) {
        const float* xr = x + (size_t)(row0 + r) * C_CH;
        #pragma unroll
        for (int g = 0; g < 4; ++g) {
            float4 v = *reinterpret_cast<const float4*>(&xr[g * 1024 + 4 * t]);
            float h0 = fmaxf(v.x + nv[g].x, 0.f);
            float h1 = fmaxf(v.y + nv[g].y, 0.f);
            float h2 = fmaxf(v.z + nv[g].z, 0.f);
            float h3 = fmaxf(v.w + nv[g].w, 0.f);
            s[g].x += h0; s[g].y += h1; s[g].z += h2; s[g].w += h3;
            q[g].x += h0*h0; q[g].y += h1*h1; q[g].z += h2*h2; q[g].w += h3*h3;
        }
    }
    #pragma unroll
    for (int g = 0; g < 4; ++g) {
        *reinterpret_cast<float4*>(&psum  [(size_t)b * C_CH + g * 1024 + 4 * t]) = s[g];
        *reinterpret_cast<float4*>(&psumsq[(size_t)b * C_CH + g * 1024 + 4 * t]) = q[g];
    }
}

// ---------------------- 2) finalize: scale/shift per channel ---------------
__global__ __launch_bounds__(256) void finalize_kernel(const float* __restrict__ psum,
                                                       const float* __restrict__ psumsq,
                                                       const float* __restrict__ gamma,
                                                       const float* __restrict__ beta,
                                                       float* __restrict__ scale,
                                                       float* __restrict__ shift) {
    const int c = blockIdx.x * 256 + threadIdx.x;
    float s = 0.f, q = 0.f;
    for (int bk = 0; bk < 512; ++bk) {
        s += psum  [(size_t)bk * C_CH + c];
        q += psumsq[(size_t)bk * C_CH + c];
    }
    const float inv = 1.f / (float)B_ROWS;
    const float mean = s * inv;
    const float var  = fmaxf(q * inv - mean * mean, 0.f);
    const float sc   = gamma[c] / sqrtf(var + 0.8f);
    scale[c] = sc;
    shift[c] = beta[c] - mean * sc;
}

// ---------------------- 3) fused conversion: A (hn->bf16) + W (->bf16) -----
__global__ __launch_bounds__(256) void conv_kernel(const float* __restrict__ x,
                                                   const float* __restrict__ scale,
                                                   const float* __restrict__ shift,
                                                   unsigned short* __restrict__ Abf,
                                                   const float* __restrict__ W,
                                                   unsigned short* __restrict__ Wbf) {
    const int bid = blockIdx.x;
    if (bid < 2048) {
        const size_t total4 = (size_t)B_ROWS * C_CH / 4;
        for (size_t i = (size_t)bid * 256 + threadIdx.x; i < total4;
             i += (size_t)2048 * 256) {
            const size_t e = i * 4;
            const int c = (int)(e & (C_CH - 1));
            float4 v  = *reinterpret_cast<const float4*>(&x[e]);
            float4 nv = *reinterpret_cast<const float4*>(&NOISE.v[c]);
            float4 sc = *reinterpret_cast<const float4*>(&scale[c]);
            float4 sh = *reinterpret_cast<const float4*>(&shift[c]);
            ushort4 o;
            o.x = f2bf(fmaxf(v.x + nv.x, 0.f) * sc.x + sh.x);
            o.y = f2bf(fmaxf(v.y + nv.y, 0.f) * sc.y + sh.y);
            o.z = f2bf(fmaxf(v.z + nv.z, 0.f) * sc.z + sh.z);
            o.w = f2bf(fmaxf(v.w + nv.w, 0.f) * sc.w + sh.w);
            *reinterpret_cast<ushort4*>(&Abf[e]) = o;
        }
    } else {
        const int vb = bid - 2048;
        const size_t total4 = (size_t)N_OUT * C_CH / 4;
        for (size_t i = (size_t)vb * 256 + threadIdx.x; i < total4;
             i += (size_t)1024 * 256) {
            const size_t e = i * 4;
            float4 v = *reinterpret_cast<const float4*>(&W[e]);
            ushort4 o;
            o.x = f2bf(v.x); o.y = f2bf(v.y); o.z = f2bf(v.z); o.w = f2bf(v.w);
            *reinterpret_cast<ushort4*>(&Wbf[e]) = o;
        }
    }
}

// ---------------------- 5) GEMM 256x256x64, 8 waves, m201 8-phase ----------
// LDS buffer (65536 B): A [256 rows][64 k] at +0 in 4 chunks of 64 rows
// (A0@0, A1@8192, A2@16384, A3@24576); B likewise at +32768 (B0..B3).
// T2 swizzle: within a row (8 x 16B slots) stored slot = slot ^ (row&7);
// global_load_lds writes linearly, SOURCE is pre-swizzled (both-sides rule).
//
// Phase structure (m201 template): per phase
//   {stage gloads | ds_read subtile | [counted vmcnt]} -> BARRIER ->
//   lgkmcnt(0)+sched_barrier(0) -> setprio(1) -> 16 MFMA -> setprio(0) -> BARRIER
// 8 barriers/K-tile. Stage order for tile t+1: ph0 {B0-3}, ph1 {A0,A2},
// ph2 {A1,A3}. Ledger (per wave):
//   ph1 wait vmcnt(6): outstanding = A1,A3(t) + B0-3(t+1) + A0,A2(t+1) = 8;
//                      certifies A1,A3(t) for ph2 reads (3-phase flight).
//   ph3 wait vmcnt(2): outstanding = 8 of tile t+1; certifies its ph0-set
//                      {B0-3,A0,A2} for next tile's ph0 reads (>=2.5-ph flight).
// Never vmcnt(0) in steady state; tail tile uses vmcnt(0).

template<int MH, int NH>
__device__ __forceinline__ void quad_mfma(bf16x8 (&af)[4][2], bf16x8 (&bfr)[4][2],
                                          f32x4 (&acc)[8][4]) {
    #pragma unroll
    for (int s = 0; s < 2; ++s)
        #pragma unroll
        for (int m = 0; m < 4; ++m)
            #pragma unroll
            for (int n = 0; n < 2; ++n)
                acc[MH * 4 + m][NH * 2 + n] = __builtin_amdgcn_mfma_f32_16x16x32_bf16(
                    af[m][s], bfr[NH * 2 + n][s], acc[MH * 4 + m][NH * 2 + n], 0, 0, 0);
}

template<bool STG>
__device__ __forceinline__ void tile_step(
    char* lds, const int bc, const int bn,
    const char*& pA0, const char*& pA1, const char*& pA2, const char*& pA3,
    const char*& pB0, const char*& pB1, const char*& pB2, const char*& pB3,
    const int dstw, const int aoff0, const int aoff1,
    const int boff0, const int boff1,
    f32x4 (&acc)[8][4]) {

    bf16x8 af[4][2], bfr[4][2];

    // ======== phase 0: quad(m0-3, n0-1) ========
    if (STG) {
        gload16(pB0, lds + bn + 32768 + dstw);
        gload16(pB1, lds + bn + 40960 + dstw);
        gload16(pB2, lds + bn + 49152 + dstw);
        gload16(pB3, lds + bn + 57344 + dstw);
    }
    #pragma unroll
    for (int m = 0; m < 4; ++m) {
        af[m][0] = *reinterpret_cast<const bf16x8*>(lds + bc + aoff0 + m * 2048);
        af[m][1] = *reinterpret_cast<const bf16x8*>(lds + bc + aoff1 + m * 2048);
    }
    #pragma unroll
    for (int n = 0; n < 2; ++n) {
        bfr[n][0] = *reinterpret_cast<const bf16x8*>(lds + bc + boff0 + n * 2048);
        bfr[n][1] = *reinterpret_cast<const bf16x8*>(lds + bc + boff1 + n * 2048);
    }
    BARRIER(); LGKM0();
    __builtin_amdgcn_s_setprio(1);
    quad_mfma<0, 0>(af, bfr, acc);
    __builtin_amdgcn_s_setprio(0);
    BARRIER();

    // ======== phase 1: quad(m0-3, n2-3) ========
    if (STG) {
        gload16(pA0, lds + bn +     0 + dstw);
        gload16(pA2, lds + bn + 16384 + dstw);
    }
    #pragma unroll
    for (int n = 2; n < 4; ++n) {
        bfr[n][0] = *reinterpret_cast<const bf16x8*>(lds + bc + boff0 + n * 2048);
        bfr[n][1] = *reinterpret_cast<const bf16x8*>(lds + bc + boff1 + n * 2048);
    }
    if (STG) asm volatile("s_waitcnt vmcnt(6)" ::: "memory");  // A1,A3(t) landed
    else     asm volatile("s_waitcnt vmcnt(0)" ::: "memory");
    BARRIER(); LGKM0();
    __builtin_amdgcn_s_setprio(1);
    quad_mfma<0, 1>(af, bfr, acc);
    __builtin_amdgcn_s_setprio(0);
    BARRIER();

    // ======== phase 2: quad(m4-7, n2-3) ========
    if (STG) {
        gload16(pA1, lds + bn +  8192 + dstw);
        gload16(pA3, lds + bn + 24576 + dstw);
        pA0 += 128; pA1 += 128; pA2 += 128; pA3 += 128;
        pB0 += 128; pB1 += 128; pB2 += 128; pB3 += 128;
    }
    #pragma unroll
    for (int m = 0; m < 4; ++m) {
        af[m][0] = *reinterpret_cast<const bf16x8*>(lds + bc + aoff0 + (m + 4) * 2048);
        af[m][1] = *reinterpret_cast<const bf16x8*>(lds + bc + aoff1 + (m + 4) * 2048);
    }
    BARRIER(); LGKM0();
    __builtin_amdgcn_s_setprio(1);
    quad_mfma<1, 1>(af, bfr, acc);
    __builtin_amdgcn_s_setprio(0);
    BARRIER();

    // ======== phase 3: quad(m4-7, n0-1); no new ds_reads ========
    if (STG) asm volatile("s_waitcnt vmcnt(2)" ::: "memory");  // ph0-set(t+1) landed
    else     asm volatile("s_waitcnt vmcnt(0)" ::: "memory");
    BARRIER();
    __builtin_amdgcn_s_setprio(1);
    quad_mfma<1, 0>(af, bfr, acc);
    __builtin_amdgcn_s_setprio(0);
    BARRIER();
}

__global__ __launch_bounds__(512, 2) void gemm256_kernel(
    const unsigned short* __restrict__ A, const unsigned short* __restrict__ B,
    const float* __restrict__ bias, float* __restrict__ C) {
    constexpr int K = C_CH, N = N_OUT;
    __shared__ alignas(128) char lds[131072];

    // XCD-bijective swizzle (nwg = 512, % 8 == 0)
    const int nwg = gridDim.x;
    const int cpx = nwg >> 3;
    int wg = blockIdx.x;
    wg = (wg & 7) * cpx + (wg >> 3);
    const int nbx = N >> 8;                 // 16
    const int bx = wg % nbx, by = wg / nbx;
    const int row0 = by << 8, col0 = bx << 8;

    const int t    = threadIdx.x;
    const int lane = t & 63;
    const int wid  = t >> 6;
    const int wm   = wid >> 2;              // 0..1
    const int wn   = wid & 3;               // 0..3
    const int l15  = lane & 15;
    const int lh   = lane >> 4;             // 0..3

    // staging source (pre-swizzled slot) and wave-uniform LDS dest
    const int sslot = (lane & 7) ^ (lane >> 3);
    const int dstw  = wid << 10;            // wid * 1024

    const char* pA0 = (const char*)A +
        ((size_t)(row0 + wid * 8 + (lane >> 3)) * K) * 2 + sslot * 16;
    const char* pA1 = pA0 + 1 * 64 * K * 2;
    const char* pA2 = pA0 + 2 * 64 * K * 2;
    const char* pA3 = pA0 + 3 * 64 * K * 2;
    const char* pB0 = (const char*)B +
        ((size_t)(col0 + wid * 8 + (lane >> 3)) * K) * 2 + sslot * 16;
    const char* pB1 = pB0 + 1 * 64 * K * 2;
    const char* pB2 = pB0 + 2 * 64 * K * 2;
    const char* pB3 = pB0 + 3 * 64 * K * 2;

    // fragment read offsets (T2 swizzle: slot ^ (row&7), row&7 == l15&7)
    const int x7 = l15 & 7;
    const int aoff0 = wm * 16384 + l15 * 128 + ((lh     ) ^ x7) * 16;
    const int aoff1 = wm * 16384 + l15 * 128 + ((lh +  4) ^ x7) * 16;
    const int boff0 = 32768 + wn * 8192 + l15 * 128 + ((lh    ) ^ x7) * 16;
    const int boff1 = 32768 + wn * 8192 + l15 * 128 + ((lh + 4) ^ x7) * 16;

    f32x4 acc[8][4];
    #pragma unroll
    for (int m = 0; m < 8; ++m)
        #pragma unroll
        for (int n = 0; n < 4; ++n)
            acc[m][n] = (f32x4){0.f, 0.f, 0.f, 0.f};

    // prologue: stage tile 0 into buf0, need-ordered
    gload16(pB0, lds + 32768 + dstw);
    gload16(pB1, lds + 40960 + dstw);
    gload16(pB2, lds + 49152 + dstw);
    gload16(pB3, lds + 57344 + dstw);
    gload16(pA0, lds +     0 + dstw);
    gload16(pA2, lds + 16384 + dstw);
    gload16(pA1, lds +  8192 + dstw);
    gload16(pA3, lds + 24576 + dstw);
    pA0 += 128; pA1 += 128; pA2 += 128; pA3 += 128;
    pB0 += 128; pB1 += 128; pB2 += 128; pB3 += 128;
    asm volatile("s_waitcnt vmcnt(2)" ::: "memory");   // ph0-set of tile 0
    BARRIER();

    // 64 K-tiles: 31 double iterations + staged tile + tail tile
    #pragma unroll 1
    for (int it = 0; it < 31; ++it) {
        tile_step<true >(lds,     0, 65536, pA0, pA1, pA2, pA3, pB0, pB1, pB2, pB3,
                         dstw, aoff0, aoff1, boff0, boff1, acc);
        tile_step<true >(lds, 65536,     0, pA0, pA1, pA2, pA3, pB0, pB1, pB2, pB3,
                         dstw, aoff0, aoff1, boff0, boff1, acc);
    }
    tile_step<true >(lds,     0, 65536, pA0, pA1, pA2, pA3, pB0, pB1, pB2, pB3,
                     dstw, aoff0, aoff1, boff0, boff1, acc);
    tile_step<false>(lds, 65536,     0, pA0, pA1, pA2, pA3, pB0, pB1, pB2, pB3,
                     dstw, aoff0, aoff1, boff0, boff1, acc);

    // epilogue: C[row][col] = acc + bias[col]
    const int crow0 = row0 + wm * 128 + lh * 4;
    const int ccol0 = col0 + wn * 64 + l15;
    #pragma unroll
    for (int n = 0; n < 4; ++n) {
        const float bv = bias[ccol0 + n * 16];
        #pragma unroll
        for (int m = 0; m < 8; ++m) {
            const size_t base = (size_t)(crow0 + m * 16) * N + (ccol0 + n * 16);
            #pragma unroll
            for (int j = 0; j < 4; ++j)
                C[base + (size_t)j * N] = acc[m][n][j] + bv;
        }
    }
}

// ---------------------- launch --------------------------------------------
extern "C" void kernel_launch(void* const* d_in, const int* in_sizes, int n_in,
                              void* d_out, int out_size, void* d_ws, size_t ws_size,
                              hipStream_t stream) {
    const float* x     = (const float*)d_in[0];
    const float* gamma = (const float*)d_in[1];
    const float* beta  = (const float*)d_in[2];
    const float* W     = (const float*)d_in[3];
    const float* b     = (const float*)d_in[4];
    float* out = (float*)d_out;

    char* ws = (char*)d_ws;
    unsigned short* Abf = (unsigned short*)(ws);                       // 64 MiB
    unsigned short* Wbf = (unsigned short*)(ws + 67108864);            // 32 MiB
    float* psum   = (float*)(ws + 100663296);                          // 8 MiB
    float* psumsq = (float*)(ws + 100663296 + 8388608);                // 8 MiB
    float* scale  = (float*)(ws + 100663296 + 16777216);               // 16 KiB
    float* shift  = (float*)(ws + 100663296 + 16777216 + 16384);       // 16 KiB

    hipLaunchKernelGGL(stats_kernel,    dim3(512),  dim3(256), 0, stream, x, psum, psumsq);
    hipLaunchKernelGGL(finalize_kernel, dim3(16),   dim3(256), 0, stream,
                       psum, psumsq, gamma, beta, scale, shift);
    hipLaunchKernelGGL(conv_kernel,     dim3(3072), dim3(256), 0, stream,
                       x, scale, shift, Abf, W, Wbf);
    hipLaunchKernelGGL(gemm256_kernel,  dim3(512),  dim3(512), 0, stream,
                       Abf, Wbf, b, out);
}

// Round 6
// 333.330 us; speedup vs baseline: 1.1492x; 1.1342x over previous
//
#include <hip/hip_runtime.h>

// ---------------------------------------------------------------------------
// Problem: h = relu(x + noise); BN1d(train, eps=0.8); z = hn @ W^T + b
// Folded form: z = h @ (scale*W)^T + (b + W @ shift),  h = relu(x+noise)
// x: [8192, 4096] f32, W: [4096, 4096] f32, out: [8192, 4096] f32
// ---------------------------------------------------------------------------

#define B_ROWS 8192
#define C_CH   4096
#define N_OUT  4096

// ---------------------- compile-time noise table --------------------------
struct alignas(16) NoiseTable { float v[C_CH]; };

constexpr NoiseTable make_noise() {
    unsigned s = 123u;
    unsigned pool[C_CH] = {};
    for (int i = 0; i < C_CH; ++i) { s = 65539u * s + 1u; pool[i] = s; }
    int nxt = C_CH - 1;
    NoiseTable t{};
    for (int i = 0; i < C_CH; ++i) {
        nxt = (int)(pool[nxt] % (unsigned)C_CH);
        t.v[i] = (float)((double)pool[nxt] * 1e-9);
        s = 65539u * s + 1u;
        pool[nxt] = s;
    }
    return t;
}

__device__ constexpr NoiseTable NOISE = make_noise();

// ---------------------- helpers -------------------------------------------
__device__ __forceinline__ unsigned short f2bf(float f) {
    unsigned u = __builtin_bit_cast(unsigned, f);
    unsigned r = (u + 0x7FFFu + ((u >> 16) & 1u)) >> 16;   // RNE
    return (unsigned short)r;
}

typedef __attribute__((ext_vector_type(8))) short bf16x8;
typedef __attribute__((ext_vector_type(4))) float f32x4;

__device__ __forceinline__ void gload16(const void* g, void* l) {
    __builtin_amdgcn_global_load_lds(
        (const __attribute__((address_space(1))) void*)g,
        (__attribute__((address_space(3))) void*)l, 16, 0, 0);
}

#define BARRIER()  do { __builtin_amdgcn_s_barrier(); asm volatile("" ::: "memory"); } while (0)
#define LGKM0()    do { asm volatile("s_waitcnt lgkmcnt(0)" ::: "memory"); \
                        __builtin_amdgcn_sched_barrier(0); } while (0)

// ------- 1) fused: h = relu(x+noise) -> bf16, + per-block BN partials -------
// 512 blocks x 16 rows each; thread t owns channels {g*1024 + 4t .. +3}.
__global__ __launch_bounds__(256) void conv_h_kernel(const float* __restrict__ x,
                                                     unsigned short* __restrict__ Hbf,
                                                     float* __restrict__ psum,
                                                     float* __restrict__ psumsq) {
    const int t = threadIdx.x;
    const int b = blockIdx.x;

    float4 nv[4];
    #pragma unroll
    for (int g = 0; g < 4; ++g)
        nv[g] = *reinterpret_cast<const float4*>(&NOISE.v[g * 1024 + 4 * t]);

    float4 s[4], q[4];
    #pragma unroll
    for (int g = 0; g < 4; ++g) { s[g] = make_float4(0,0,0,0); q[g] = make_float4(0,0,0,0); }

    const int row0 = b * 16;
    for (int r = 0; r < 16; ++r) {
        const size_t rb = (size_t)(row0 + r) * C_CH;
        const float* xr = x + rb;
        #pragma unroll
        for (int g = 0; g < 4; ++g) {
            float4 v = *reinterpret_cast<const float4*>(&xr[g * 1024 + 4 * t]);
            float h0 = fmaxf(v.x + nv[g].x, 0.f);
            float h1 = fmaxf(v.y + nv[g].y, 0.f);
            float h2 = fmaxf(v.z + nv[g].z, 0.f);
            float h3 = fmaxf(v.w + nv[g].w, 0.f);
            s[g].x += h0; s[g].y += h1; s[g].z += h2; s[g].w += h3;
            q[g].x += h0*h0; q[g].y += h1*h1; q[g].z += h2*h2; q[g].w += h3*h3;
            ushort4 o;
            o.x = f2bf(h0); o.y = f2bf(h1); o.z = f2bf(h2); o.w = f2bf(h3);
            *reinterpret_cast<ushort4*>(&Hbf[rb + g * 1024 + 4 * t]) = o;
        }
    }
    #pragma unroll
    for (int g = 0; g < 4; ++g) {
        *reinterpret_cast<float4*>(&psum  [(size_t)b * C_CH + g * 1024 + 4 * t]) = s[g];
        *reinterpret_cast<float4*>(&psumsq[(size_t)b * C_CH + g * 1024 + 4 * t]) = q[g];
    }
}

// ---------------------- 2) finalize: scale/shift per channel ---------------
__global__ __launch_bounds__(256) void finalize_kernel(const float* __restrict__ psum,
                                                       const float* __restrict__ psumsq,
                                                       const float* __restrict__ gamma,
                                                       const float* __restrict__ beta,
                                                       float* __restrict__ scale,
                                                       float* __restrict__ shift) {
    const int c = blockIdx.x * 256 + threadIdx.x;
    float s = 0.f, q = 0.f;
    for (int bk = 0; bk < 512; ++bk) {
        s += psum  [(size_t)bk * C_CH + c];
        q += psumsq[(size_t)bk * C_CH + c];
    }
    const float inv = 1.f / (float)B_ROWS;
    const float mean = s * inv;
    const float var  = fmaxf(q * inv - mean * mean, 0.f);
    const float sc   = gamma[c] / sqrtf(var + 0.8f);
    scale[c] = sc;
    shift[c] = beta[c] - mean * sc;
}

// ------- 3) convW': W' = scale*W (bf16) + bias' = b + W @ shift (f32) -------
// 1024 blocks x 4 waves; wave w owns row (blockIdx.x*4 + w). 64 lanes x
// float4 x 16 steps cover the 4096 columns; shuffle-reduce the shift-dot.
__global__ __launch_bounds__(256) void convW_kernel(const float* __restrict__ W,
                                                    const float* __restrict__ scale,
                                                    const float* __restrict__ shift,
                                                    const float* __restrict__ b,
                                                    unsigned short* __restrict__ Wbf,
                                                    float* __restrict__ biasN) {
    const int wv   = threadIdx.x >> 6;
    const int lane = threadIdx.x & 63;
    const int o    = blockIdx.x * 4 + wv;
    const float* wr = W + (size_t)o * C_CH;
    unsigned short* wo = Wbf + (size_t)o * C_CH;

    float acc = 0.f;
    #pragma unroll
    for (int s = 0; s < 16; ++s) {
        const int c = s * 256 + lane * 4;
        float4 v  = *reinterpret_cast<const float4*>(&wr[c]);
        float4 sc = *reinterpret_cast<const float4*>(&scale[c]);
        float4 sh = *reinterpret_cast<const float4*>(&shift[c]);
        ushort4 ov;
        ov.x = f2bf(v.x * sc.x); ov.y = f2bf(v.y * sc.y);
        ov.z = f2bf(v.z * sc.z); ov.w = f2bf(v.w * sc.w);
        *reinterpret_cast<ushort4*>(&wo[c]) = ov;
        acc += sh.x * v.x + sh.y * v.y + sh.z * v.z + sh.w * v.w;
    }
    #pragma unroll
    for (int off = 32; off > 0; off >>= 1)
        acc += __shfl_down(acc, off);
    if (lane == 0) biasN[o] = b[o] + acc;
}

// ---------------------- 4) GEMM 256x256x64 (R3 schedule, best measured) ----
// LDS buffer (65536 B): A [256 rows][64 k] at +0 in 4 chunks of 64 rows
// (A0@0, A1@8192, A2@16384, A3@24576); B likewise at +32768 (B0..B3).
// T2 swizzle: within a row (8 x 16B slots) stored slot = slot ^ (row&7);
// global_load_lds writes linearly, SOURCE is pre-swizzled (both-sides rule).
//
// Per K-tile, 4 phases (quadrants), chunk needs: ph0 {B0-3,A0,A2}, ph2 {A1,A3}.
// Stage order for tile t+1: ph0 {B0,B1}, ph1 {B2,B3}, ph2 {A0,A2}, ph3 {A1,A3}
// -> per-wave outstanding bookkeeping gives vmcnt(2)@ph0, vmcnt(4)@ph2.
// 2 barriers/K-tile, each right after its counted vmcnt. Never vmcnt(0)
// except the tail tile.

template<int MH, int NH>
__device__ __forceinline__ void quad_mfma(bf16x8 (&af)[4][2], bf16x8 (&bfr)[4][2],
                                          f32x4 (&acc)[8][4]) {
    #pragma unroll
    for (int s = 0; s < 2; ++s)
        #pragma unroll
        for (int m = 0; m < 4; ++m)
            #pragma unroll
            for (int n = 0; n < 2; ++n)
                acc[MH * 4 + m][NH * 2 + n] = __builtin_amdgcn_mfma_f32_16x16x32_bf16(
                    af[m][s], bfr[NH * 2 + n][s], acc[MH * 4 + m][NH * 2 + n], 0, 0, 0);
}

template<bool STG>
__device__ __forceinline__ void tile_step(
    char* lds, const int bc, const int bn,
    const char*& pA0, const char*& pA1, const char*& pA2, const char*& pA3,
    const char*& pB0, const char*& pB1, const char*& pB2, const char*& pB3,
    const int dstw, const int aoff0, const int aoff1,
    const int boff0, const int boff1,
    f32x4 (&acc)[8][4]) {

    bf16x8 af[4][2], bfr[4][2];

    // ======== phase 0: quad(m0-3, n0-1); needs B0-3,A0,A2 (6 oldest) ========
    asm volatile("s_waitcnt vmcnt(2)" ::: "memory");
    BARRIER();                       // block-wide landing + bn reuse fence
    __builtin_amdgcn_sched_barrier(0);
    if (STG) {
        gload16(pB0, lds + bn + 32768 + dstw);
        gload16(pB1, lds + bn + 40960 + dstw);
    }
    #pragma unroll
    for (int m = 0; m < 4; ++m) {
        af[m][0] = *reinterpret_cast<const bf16x8*>(lds + bc + aoff0 + m * 2048);
        af[m][1] = *reinterpret_cast<const bf16x8*>(lds + bc + aoff1 + m * 2048);
    }
    #pragma unroll
    for (int n = 0; n < 2; ++n) {
        bfr[n][0] = *reinterpret_cast<const bf16x8*>(lds + bc + boff0 + n * 2048);
        bfr[n][1] = *reinterpret_cast<const bf16x8*>(lds + bc + boff1 + n * 2048);
    }
    LGKM0();
    __builtin_amdgcn_s_setprio(1);
    quad_mfma<0, 0>(af, bfr, acc);
    __builtin_amdgcn_s_setprio(0);

    // ======== phase 1: quad(m0-3, n2-3) ========
    if (STG) {
        gload16(pB2, lds + bn + 49152 + dstw);
        gload16(pB3, lds + bn + 57344 + dstw);
    }
    #pragma unroll
    for (int n = 2; n < 4; ++n) {
        bfr[n][0] = *reinterpret_cast<const bf16x8*>(lds + bc + boff0 + n * 2048);
        bfr[n][1] = *reinterpret_cast<const bf16x8*>(lds + bc + boff1 + n * 2048);
    }
    LGKM0();
    __builtin_amdgcn_s_setprio(1);
    quad_mfma<0, 1>(af, bfr, acc);
    __builtin_amdgcn_s_setprio(0);

    // ======== phase 2: quad(m4-7, n2-3); needs A1,A3 (2 oldest) ========
    if (STG) asm volatile("s_waitcnt vmcnt(4)" ::: "memory");
    else     asm volatile("s_waitcnt vmcnt(0)" ::: "memory");
    BARRIER();
    __builtin_amdgcn_sched_barrier(0);
    if (STG) {
        gload16(pA0, lds + bn +     0 + dstw);
        gload16(pA2, lds + bn + 16384 + dstw);
    }
    #pragma unroll
    for (int m = 0; m < 4; ++m) {
        af[m][0] = *reinterpret_cast<const bf16x8*>(lds + bc + aoff0 + (m + 4) * 2048);
        af[m][1] = *reinterpret_cast<const bf16x8*>(lds + bc + aoff1 + (m + 4) * 2048);
    }
    LGKM0();
    __builtin_amdgcn_s_setprio(1);
    quad_mfma<1, 1>(af, bfr, acc);
    __builtin_amdgcn_s_setprio(0);

    // ======== phase 3: quad(m4-7, n0-1); pure register phase ========
    if (STG) {
        gload16(pA1, lds + bn +  8192 + dstw);
        gload16(pA3, lds + bn + 24576 + dstw);
        pA0 += 128; pA1 += 128; pA2 += 128; pA3 += 128;
        pB0 += 128; pB1 += 128; pB2 += 128; pB3 += 128;
    }
    __builtin_amdgcn_s_setprio(1);
    quad_mfma<1, 0>(af, bfr, acc);
    __builtin_amdgcn_s_setprio(0);
}

__global__ __launch_bounds__(512, 2) void gemm256_kernel(
    const unsigned short* __restrict__ A, const unsigned short* __restrict__ B,
    const float* __restrict__ bias, float* __restrict__ C) {
    constexpr int K = C_CH, N = N_OUT;
    __shared__ alignas(128) char lds[131072];

    // XCD-bijective swizzle (nwg = 512, % 8 == 0)
    const int nwg = gridDim.x;
    const int cpx = nwg >> 3;
    int wg = blockIdx.x;
    wg = (wg & 7) * cpx + (wg >> 3);
    const int nbx = N >> 8;                 // 16
    const int bx = wg % nbx, by = wg / nbx;
    const int row0 = by << 8, col0 = bx << 8;

    const int t    = threadIdx.x;
    const int lane = t & 63;
    const int wid  = t >> 6;
    const int wm   = wid >> 2;              // 0..1
    const int wn   = wid & 3;               // 0..3
    const int l15  = lane & 15;
    const int lh   = lane >> 4;             // 0..3

    // staging source (pre-swizzled slot) and wave-uniform LDS dest
    const int sslot = (lane & 7) ^ (lane >> 3);
    const int dstw  = wid << 10;            // wid * 1024

    const char* pA0 = (const char*)A +
        ((size_t)(row0 + wid * 8 + (lane >> 3)) * K) * 2 + sslot * 16;
    const char* pA1 = pA0 + 1 * 64 * K * 2;
    const char* pA2 = pA0 + 2 * 64 * K * 2;
    const char* pA3 = pA0 + 3 * 64 * K * 2;
    const char* pB0 = (const char*)B +
        ((size_t)(col0 + wid * 8 + (lane >> 3)) * K) * 2 + sslot * 16;
    const char* pB1 = pB0 + 1 * 64 * K * 2;
    const char* pB2 = pB0 + 2 * 64 * K * 2;
    const char* pB3 = pB0 + 3 * 64 * K * 2;

    // fragment read offsets (T2 swizzle: slot ^ (row&7), row&7 == l15&7)
    const int x7 = l15 & 7;
    const int aoff0 = wm * 16384 + l15 * 128 + ((lh     ) ^ x7) * 16;
    const int aoff1 = wm * 16384 + l15 * 128 + ((lh +  4) ^ x7) * 16;
    const int boff0 = 32768 + wn * 8192 + l15 * 128 + ((lh    ) ^ x7) * 16;
    const int boff1 = 32768 + wn * 8192 + l15 * 128 + ((lh + 4) ^ x7) * 16;

    f32x4 acc[8][4];
    #pragma unroll
    for (int m = 0; m < 8; ++m)
        #pragma unroll
        for (int n = 0; n < 4; ++n)
            acc[m][n] = (f32x4){0.f, 0.f, 0.f, 0.f};

    // prologue: stage tile 0 into buf0 in vmcnt-matched order
    // (B0,B1,B2,B3,A0,A2 = oldest 6; A1,A3 = newest 2)
    gload16(pB0, lds + 32768 + dstw);
    gload16(pB1, lds + 40960 + dstw);
    gload16(pB2, lds + 49152 + dstw);
    gload16(pB3, lds + 57344 + dstw);
    gload16(pA0, lds +     0 + dstw);
    gload16(pA2, lds + 16384 + dstw);
    gload16(pA1, lds +  8192 + dstw);
    gload16(pA3, lds + 24576 + dstw);
    pA0 += 128; pA1 += 128; pA2 += 128; pA3 += 128;
    pB0 += 128; pB1 += 128; pB2 += 128; pB3 += 128;

    // 64 K-tiles: 31 double iterations + staged tile + tail tile
    #pragma unroll 1
    for (int it = 0; it < 31; ++it) {
        tile_step<true >(lds,     0, 65536, pA0, pA1, pA2, pA3, pB0, pB1, pB2, pB3,
                         dstw, aoff0, aoff1, boff0, boff1, acc);
        tile_step<true >(lds, 65536,     0, pA0, pA1, pA2, pA3, pB0, pB1, pB2, pB3,
                         dstw, aoff0, aoff1, boff0, boff1, acc);
    }
    tile_step<true >(lds,     0, 65536, pA0, pA1, pA2, pA3, pB0, pB1, pB2, pB3,
                     dstw, aoff0, aoff1, boff0, boff1, acc);
    tile_step<false>(lds, 65536,     0, pA0, pA1, pA2, pA3, pB0, pB1, pB2, pB3,
                     dstw, aoff0, aoff1, boff0, boff1, acc);

    // epilogue: C[row][col] = acc + bias[col]
    const int crow0 = row0 + wm * 128 + lh * 4;
    const int ccol0 = col0 + wn * 64 + l15;
    #pragma unroll
    for (int n = 0; n < 4; ++n) {
        const float bv = bias[ccol0 + n * 16];
        #pragma unroll
        for (int m = 0; m < 8; ++m) {
            const size_t base = (size_t)(crow0 + m * 16) * N + (ccol0 + n * 16);
            #pragma unroll
            for (int j = 0; j < 4; ++j)
                C[base + (size_t)j * N] = acc[m][n][j] + bv;
        }
    }
}

// ---------------------- launch --------------------------------------------
extern "C" void kernel_launch(void* const* d_in, const int* in_sizes, int n_in,
                              void* d_out, int out_size, void* d_ws, size_t ws_size,
                              hipStream_t stream) {
    const float* x     = (const float*)d_in[0];
    const float* gamma = (const float*)d_in[1];
    const float* beta  = (const float*)d_in[2];
    const float* W     = (const float*)d_in[3];
    const float* b     = (const float*)d_in[4];
    float* out = (float*)d_out;

    char* ws = (char*)d_ws;
    unsigned short* Hbf = (unsigned short*)(ws);                       // 64 MiB
    unsigned short* Wbf = (unsigned short*)(ws + 67108864);            // 32 MiB
    float* psum   = (float*)(ws + 100663296);                          // 8 MiB
    float* psumsq = (float*)(ws + 109051904);                          // 8 MiB
    float* scale  = (float*)(ws + 117440512);                          // 16 KiB
    float* shift  = (float*)(ws + 117440512 + 16384);                  // 16 KiB
    float* biasN  = (float*)(ws + 117440512 + 32768);                  // 16 KiB

    hipLaunchKernelGGL(conv_h_kernel,   dim3(512),  dim3(256), 0, stream,
                       x, Hbf, psum, psumsq);
    hipLaunchKernelGGL(finalize_kernel, dim3(16),   dim3(256), 0, stream,
                       psum, psumsq, gamma, beta, scale, shift);
    hipLaunchKernelGGL(convW_kernel,    dim3(1024), dim3(256), 0, stream,
                       W, scale, shift, b, Wbf, biasN);
    hipLaunchKernelGGL(gemm256_kernel,  dim3(512),  dim3(512), 0, stream,
                       Hbf, Wbf, biasN, out);
}

// Round 7
// 333.304 us; speedup vs baseline: 1.1493x; 1.0001x over previous
//
#include <hip/hip_runtime.h>

// ---------------------------------------------------------------------------
// Problem: h = relu(x + noise); BN1d(train, eps=0.8); z = hn @ W^T + b
// Folded form: z = h @ (scale*W)^T + (b + W @ shift),  h = relu(x+noise)
// x: [8192, 4096] f32, W: [4096, 4096] f32, out: [8192, 4096] f32
// ---------------------------------------------------------------------------

#define B_ROWS 8192
#define C_CH   4096
#define N_OUT  4096

// ---------------------- compile-time noise table --------------------------
struct alignas(16) NoiseTable { float v[C_CH]; };

constexpr NoiseTable make_noise() {
    unsigned s = 123u;
    unsigned pool[C_CH] = {};
    for (int i = 0; i < C_CH; ++i) { s = 65539u * s + 1u; pool[i] = s; }
    int nxt = C_CH - 1;
    NoiseTable t{};
    for (int i = 0; i < C_CH; ++i) {
        nxt = (int)(pool[nxt] % (unsigned)C_CH);
        t.v[i] = (float)((double)pool[nxt] * 1e-9);
        s = 65539u * s + 1u;
        pool[nxt] = s;
    }
    return t;
}

__device__ constexpr NoiseTable NOISE = make_noise();

// ---------------------- helpers -------------------------------------------
__device__ __forceinline__ unsigned short f2bf(float f) {
    unsigned u = __builtin_bit_cast(unsigned, f);
    unsigned r = (u + 0x7FFFu + ((u >> 16) & 1u)) >> 16;   // RNE
    return (unsigned short)r;
}

typedef __attribute__((ext_vector_type(8))) short bf16x8;
typedef __attribute__((ext_vector_type(4))) float f32x4;

__device__ __forceinline__ void gload16(const void* g, void* l) {
    __builtin_amdgcn_global_load_lds(
        (const __attribute__((address_space(1))) void*)g,
        (__attribute__((address_space(3))) void*)l, 16, 0, 0);
}

#define BARRIER()  do { __builtin_amdgcn_s_barrier(); asm volatile("" ::: "memory"); } while (0)
#define SCHED0()   __builtin_amdgcn_sched_barrier(0)
#define LGKM(N)    do { asm volatile("s_waitcnt lgkmcnt(" #N ")" ::: "memory"); \
                        __builtin_amdgcn_sched_barrier(0); } while (0)

// ------- 1) fused: h = relu(x+noise) -> bf16, + per-block BN partials -------
__global__ __launch_bounds__(256) void conv_h_kernel(const float* __restrict__ x,
                                                     unsigned short* __restrict__ Hbf,
                                                     float* __restrict__ psum,
                                                     float* __restrict__ psumsq) {
    const int t = threadIdx.x;
    const int b = blockIdx.x;

    float4 nv[4];
    #pragma unroll
    for (int g = 0; g < 4; ++g)
        nv[g] = *reinterpret_cast<const float4*>(&NOISE.v[g * 1024 + 4 * t]);

    float4 s[4], q[4];
    #pragma unroll
    for (int g = 0; g < 4; ++g) { s[g] = make_float4(0,0,0,0); q[g] = make_float4(0,0,0,0); }

    const int row0 = b * 16;
    for (int r = 0; r < 16; ++r) {
        const size_t rb = (size_t)(row0 + r) * C_CH;
        const float* xr = x + rb;
        #pragma unroll
        for (int g = 0; g < 4; ++g) {
            float4 v = *reinterpret_cast<const float4*>(&xr[g * 1024 + 4 * t]);
            float h0 = fmaxf(v.x + nv[g].x, 0.f);
            float h1 = fmaxf(v.y + nv[g].y, 0.f);
            float h2 = fmaxf(v.z + nv[g].z, 0.f);
            float h3 = fmaxf(v.w + nv[g].w, 0.f);
            s[g].x += h0; s[g].y += h1; s[g].z += h2; s[g].w += h3;
            q[g].x += h0*h0; q[g].y += h1*h1; q[g].z += h2*h2; q[g].w += h3*h3;
            ushort4 o;
            o.x = f2bf(h0); o.y = f2bf(h1); o.z = f2bf(h2); o.w = f2bf(h3);
            *reinterpret_cast<ushort4*>(&Hbf[rb + g * 1024 + 4 * t]) = o;
        }
    }
    #pragma unroll
    for (int g = 0; g < 4; ++g) {
        *reinterpret_cast<float4*>(&psum  [(size_t)b * C_CH + g * 1024 + 4 * t]) = s[g];
        *reinterpret_cast<float4*>(&psumsq[(size_t)b * C_CH + g * 1024 + 4 * t]) = q[g];
    }
}

// ---------------------- 2) finalize: scale/shift per channel ---------------
__global__ __launch_bounds__(256) void finalize_kernel(const float* __restrict__ psum,
                                                       const float* __restrict__ psumsq,
                                                       const float* __restrict__ gamma,
                                                       const float* __restrict__ beta,
                                                       float* __restrict__ scale,
                                                       float* __restrict__ shift) {
    const int c = blockIdx.x * 256 + threadIdx.x;
    float s = 0.f, q = 0.f;
    for (int bk = 0; bk < 512; ++bk) {
        s += psum  [(size_t)bk * C_CH + c];
        q += psumsq[(size_t)bk * C_CH + c];
    }
    const float inv = 1.f / (float)B_ROWS;
    const float mean = s * inv;
    const float var  = fmaxf(q * inv - mean * mean, 0.f);
    const float sc   = gamma[c] / sqrtf(var + 0.8f);
    scale[c] = sc;
    shift[c] = beta[c] - mean * sc;
}

// ------- 3) convW': W' = scale*W (bf16) + bias' = b + W @ shift (f32) -------
__global__ __launch_bounds__(256) void convW_kernel(const float* __restrict__ W,
                                                    const float* __restrict__ scale,
                                                    const float* __restrict__ shift,
                                                    const float* __restrict__ b,
                                                    unsigned short* __restrict__ Wbf,
                                                    float* __restrict__ biasN) {
    const int wv   = threadIdx.x >> 6;
    const int lane = threadIdx.x & 63;
    const int o    = blockIdx.x * 4 + wv;
    const float* wr = W + (size_t)o * C_CH;
    unsigned short* wo = Wbf + (size_t)o * C_CH;

    float acc = 0.f;
    #pragma unroll
    for (int s = 0; s < 16; ++s) {
        const int c = s * 256 + lane * 4;
        float4 v  = *reinterpret_cast<const float4*>(&wr[c]);
        float4 sc = *reinterpret_cast<const float4*>(&scale[c]);
        float4 sh = *reinterpret_cast<const float4*>(&shift[c]);
        ushort4 ov;
        ov.x = f2bf(v.x * sc.x); ov.y = f2bf(v.y * sc.y);
        ov.z = f2bf(v.z * sc.z); ov.w = f2bf(v.w * sc.w);
        *reinterpret_cast<ushort4*>(&wo[c]) = ov;
        acc += sh.x * v.x + sh.y * v.y + sh.z * v.z + sh.w * v.w;
    }
    #pragma unroll
    for (int off = 32; off > 0; off >>= 1)
        acc += __shfl_down(acc, off);
    if (lane == 0) biasN[o] = b[o] + acc;
}

// ---------------------- 4) GEMM 256x256x64, lgkm-pipelined fragments -------
// R3 skeleton unchanged: LDS buffer 65536 B, A chunks A0..A3 (64 rows each)
// at 0/8192/16384/24576, B chunks at +32768. T2 swizzle slot^(row&7), source
// pre-swizzled. Stage order for t+1: ph0 {B0,B1}, ph1 {B2,B3}, ph2 {A0,A2},
// ph3 {A1,A3}; waits vmcnt(2)@barrier1, vmcnt(4)@barrier2. 2 barriers/K-tile.
//
// NEW vs R6: fragment ds_reads are issued in sched_barrier-ordered groups as
// early as their certifying barrier allows, and waited with COUNTED lgkmcnt —
// Q00 overlaps bf23's reads, the m4-5 MFMA overlap m6-7's reads. (The old
// LGKM0-after-every-burst forced read/MFMA serialization per wave — that was
// the ~49% stall.)

template<int MH, int NH>
__device__ __forceinline__ void quad_mfma(bf16x8 (&af)[4][2], bf16x8 (&bfr)[4][2],
                                          f32x4 (&acc)[8][4]) {
    #pragma unroll
    for (int s = 0; s < 2; ++s)
        #pragma unroll
        for (int m = 0; m < 4; ++m)
            #pragma unroll
            for (int n = 0; n < 2; ++n)
                acc[MH * 4 + m][NH * 2 + n] = __builtin_amdgcn_mfma_f32_16x16x32_bf16(
                    af[m][s], bfr[NH * 2 + n][s], acc[MH * 4 + m][NH * 2 + n], 0, 0, 0);
}

template<bool STG>
__device__ __forceinline__ void tile_step(
    char* lds, const int bc, const int bn,
    const char*& pA0, const char*& pA1, const char*& pA2, const char*& pA3,
    const char*& pB0, const char*& pB1, const char*& pB2, const char*& pB3,
    const int dstw, const int aoff0, const int aoff1,
    const int boff0, const int boff1,
    f32x4 (&acc)[8][4]) {

    bf16x8 af[4][2], bfr[4][2];

    // ======== first half: Q00 + Q01 ========
    asm volatile("s_waitcnt vmcnt(2)" ::: "memory");   // B0-3,A0,A2 of t landed
    BARRIER();                        // block-wide landing + bn reuse fence
    SCHED0();
    if (STG) {
        gload16(pB0, lds + bn + 32768 + dstw);
        gload16(pB1, lds + bn + 40960 + dstw);
    }
    // group 1 (12 reads): af m0-3 both k-slots + bf n0-1
    #pragma unroll
    for (int m = 0; m < 4; ++m) {
        af[m][0] = *reinterpret_cast<const bf16x8*>(lds + bc + aoff0 + m * 2048);
        af[m][1] = *reinterpret_cast<const bf16x8*>(lds + bc + aoff1 + m * 2048);
    }
    #pragma unroll
    for (int n = 0; n < 2; ++n) {
        bfr[n][0] = *reinterpret_cast<const bf16x8*>(lds + bc + boff0 + n * 2048);
        bfr[n][1] = *reinterpret_cast<const bf16x8*>(lds + bc + boff1 + n * 2048);
    }
    SCHED0();
    // group 2 (4 reads): bf n2-3
    #pragma unroll
    for (int n = 2; n < 4; ++n) {
        bfr[n][0] = *reinterpret_cast<const bf16x8*>(lds + bc + boff0 + n * 2048);
        bfr[n][1] = *reinterpret_cast<const bf16x8*>(lds + bc + boff1 + n * 2048);
    }
    LGKM(4);                          // group 1 done; group 2 drains under Q00
    __builtin_amdgcn_s_setprio(1);
    quad_mfma<0, 0>(af, bfr, acc);
    __builtin_amdgcn_s_setprio(0);
    if (STG) {
        gload16(pB2, lds + bn + 49152 + dstw);
        gload16(pB3, lds + bn + 57344 + dstw);
    }
    LGKM(0);                          // group 2 done
    __builtin_amdgcn_s_setprio(1);
    quad_mfma<0, 1>(af, bfr, acc);
    __builtin_amdgcn_s_setprio(0);

    // ======== second half: Q11 + Q10 ========
    if (STG) asm volatile("s_waitcnt vmcnt(4)" ::: "memory");  // A1,A3 of t landed
    else     asm volatile("s_waitcnt vmcnt(0)" ::: "memory");
    BARRIER();
    SCHED0();
    if (STG) {
        gload16(pA0, lds + bn +     0 + dstw);
        gload16(pA2, lds + bn + 16384 + dstw);
    }
    // group 3 (4 reads): af[0..1] <- phys rows m4,m5
    #pragma unroll
    for (int m = 0; m < 2; ++m) {
        af[m][0] = *reinterpret_cast<const bf16x8*>(lds + bc + aoff0 + (m + 4) * 2048);
        af[m][1] = *reinterpret_cast<const bf16x8*>(lds + bc + aoff1 + (m + 4) * 2048);
    }
    SCHED0();
    // group 4 (4 reads): af[2..3] <- phys rows m6,m7
    #pragma unroll
    for (int m = 2; m < 4; ++m) {
        af[m][0] = *reinterpret_cast<const bf16x8*>(lds + bc + aoff0 + (m + 4) * 2048);
        af[m][1] = *reinterpret_cast<const bf16x8*>(lds + bc + aoff1 + (m + 4) * 2048);
    }
    LGKM(4);                          // group 3 done; group 4 drains under MFMA
    __builtin_amdgcn_s_setprio(1);
    #pragma unroll
    for (int s = 0; s < 2; ++s)
        #pragma unroll
        for (int m = 0; m < 2; ++m)
            #pragma unroll
            for (int n = 2; n < 4; ++n)
                acc[4 + m][n] = __builtin_amdgcn_mfma_f32_16x16x32_bf16(
                    af[m][s], bfr[n][s], acc[4 + m][n], 0, 0, 0);
    __builtin_amdgcn_s_setprio(0);
    if (STG) {
        gload16(pA1, lds + bn +  8192 + dstw);
        gload16(pA3, lds + bn + 24576 + dstw);
        pA0 += 128; pA1 += 128; pA2 += 128; pA3 += 128;
        pB0 += 128; pB1 += 128; pB2 += 128; pB3 += 128;
    }
    LGKM(0);                          // group 4 done
    __builtin_amdgcn_s_setprio(1);
    #pragma unroll
    for (int s = 0; s < 2; ++s)
        #pragma unroll
        for (int m = 2; m < 4; ++m)
            #pragma unroll
            for (int n = 2; n < 4; ++n)
                acc[4 + m][n] = __builtin_amdgcn_mfma_f32_16x16x32_bf16(
                    af[m][s], bfr[n][s], acc[4 + m][n], 0, 0, 0);
    // Q10: pure register
    #pragma unroll
    for (int s = 0; s < 2; ++s)
        #pragma unroll
        for (int m = 0; m < 4; ++m)
            #pragma unroll
            for (int n = 0; n < 2; ++n)
                acc[4 + m][n] = __builtin_amdgcn_mfma_f32_16x16x32_bf16(
                    af[m][s], bfr[n][s], acc[4 + m][n], 0, 0, 0);
    __builtin_amdgcn_s_setprio(0);
}

__global__ __launch_bounds__(512, 2) void gemm256_kernel(
    const unsigned short* __restrict__ A, const unsigned short* __restrict__ B,
    const float* __restrict__ bias, float* __restrict__ C) {
    constexpr int K = C_CH, N = N_OUT;
    __shared__ alignas(128) char lds[131072];

    // XCD-bijective swizzle (nwg = 512, % 8 == 0)
    const int nwg = gridDim.x;
    const int cpx = nwg >> 3;
    int wg = blockIdx.x;
    wg = (wg & 7) * cpx + (wg >> 3);
    const int nbx = N >> 8;                 // 16
    const int bx = wg % nbx, by = wg / nbx;
    const int row0 = by << 8, col0 = bx << 8;

    const int t    = threadIdx.x;
    const int lane = t & 63;
    const int wid  = t >> 6;
    const int wm   = wid >> 2;              // 0..1
    const int wn   = wid & 3;               // 0..3
    const int l15  = lane & 15;
    const int lh   = lane >> 4;             // 0..3

    // staging source (pre-swizzled slot) and wave-uniform LDS dest
    const int sslot = (lane & 7) ^ (lane >> 3);
    const int dstw  = wid << 10;            // wid * 1024

    const char* pA0 = (const char*)A +
        ((size_t)(row0 + wid * 8 + (lane >> 3)) * K) * 2 + sslot * 16;
    const char* pA1 = pA0 + 1 * 64 * K * 2;
    const char* pA2 = pA0 + 2 * 64 * K * 2;
    const char* pA3 = pA0 + 3 * 64 * K * 2;
    const char* pB0 = (const char*)B +
        ((size_t)(col0 + wid * 8 + (lane >> 3)) * K) * 2 + sslot * 16;
    const char* pB1 = pB0 + 1 * 64 * K * 2;
    const char* pB2 = pB0 + 2 * 64 * K * 2;
    const char* pB3 = pB0 + 3 * 64 * K * 2;

    // fragment read offsets (T2 swizzle: slot ^ (row&7), row&7 == l15&7)
    const int x7 = l15 & 7;
    const int aoff0 = wm * 16384 + l15 * 128 + ((lh     ) ^ x7) * 16;
    const int aoff1 = wm * 16384 + l15 * 128 + ((lh +  4) ^ x7) * 16;
    const int boff0 = 32768 + wn * 8192 + l15 * 128 + ((lh    ) ^ x7) * 16;
    const int boff1 = 32768 + wn * 8192 + l15 * 128 + ((lh + 4) ^ x7) * 16;

    f32x4 acc[8][4];
    #pragma unroll
    for (int m = 0; m < 8; ++m)
        #pragma unroll
        for (int n = 0; n < 4; ++n)
            acc[m][n] = (f32x4){0.f, 0.f, 0.f, 0.f};

    // prologue: stage tile 0 into buf0 in vmcnt-matched order
    // (B0,B1,B2,B3,A0,A2 = oldest 6; A1,A3 = newest 2)
    gload16(pB0, lds + 32768 + dstw);
    gload16(pB1, lds + 40960 + dstw);
    gload16(pB2, lds + 49152 + dstw);
    gload16(pB3, lds + 57344 + dstw);
    gload16(pA0, lds +     0 + dstw);
    gload16(pA2, lds + 16384 + dstw);
    gload16(pA1, lds +  8192 + dstw);
    gload16(pA3, lds + 24576 + dstw);
    pA0 += 128; pA1 += 128; pA2 += 128; pA3 += 128;
    pB0 += 128; pB1 += 128; pB2 += 128; pB3 += 128;

    // 64 K-tiles: 31 double iterations + staged tile + tail tile
    #pragma unroll 1
    for (int it = 0; it < 31; ++it) {
        tile_step<true >(lds,     0, 65536, pA0, pA1, pA2, pA3, pB0, pB1, pB2, pB3,
                         dstw, aoff0, aoff1, boff0, boff1, acc);
        tile_step<true >(lds, 65536,     0, pA0, pA1, pA2, pA3, pB0, pB1, pB2, pB3,
                         dstw, aoff0, aoff1, boff0, boff1, acc);
    }
    tile_step<true >(lds,     0, 65536, pA0, pA1, pA2, pA3, pB0, pB1, pB2, pB3,
                     dstw, aoff0, aoff1, boff0, boff1, acc);
    tile_step<false>(lds, 65536,     0, pA0, pA1, pA2, pA3, pB0, pB1, pB2, pB3,
                     dstw, aoff0, aoff1, boff0, boff1, acc);

    // epilogue: C[row][col] = acc + bias[col]
    const int crow0 = row0 + wm * 128 + lh * 4;
    const int ccol0 = col0 + wn * 64 + l15;
    #pragma unroll
    for (int n = 0; n < 4; ++n) {
        const float bv = bias[ccol0 + n * 16];
        #pragma unroll
        for (int m = 0; m < 8; ++m) {
            const size_t base = (size_t)(crow0 + m * 16) * N + (ccol0 + n * 16);
            #pragma unroll
            for (int j = 0; j < 4; ++j)
                C[base + (size_t)j * N] = acc[m][n][j] + bv;
        }
    }
}

// ---------------------- launch --------------------------------------------
extern "C" void kernel_launch(void* const* d_in, const int* in_sizes, int n_in,
                              void* d_out, int out_size, void* d_ws, size_t ws_size,
                              hipStream_t stream) {
    const float* x     = (const float*)d_in[0];
    const float* gamma = (const float*)d_in[1];
    const float* beta  = (const float*)d_in[2];
    const float* W     = (const float*)d_in[3];
    const float* b     = (const float*)d_in[4];
    float* out = (float*)d_out;

    char* ws = (char*)d_ws;
    unsigned short* Hbf = (unsigned short*)(ws);                       // 64 MiB
    unsigned short* Wbf = (unsigned short*)(ws + 67108864);            // 32 MiB
    float* psum   = (float*)(ws + 100663296);                          // 8 MiB
    float* psumsq = (float*)(ws + 109051904);                          // 8 MiB
    float* scale  = (float*)(ws + 117440512);                          // 16 KiB
    float* shift  = (float*)(ws + 117440512 + 16384);                  // 16 KiB
    float* biasN  = (float*)(ws + 117440512 + 32768);                  // 16 KiB

    hipLaunchKernelGGL(conv_h_kernel,   dim3(512),  dim3(256), 0, stream,
                       x, Hbf, psum, psumsq);
    hipLaunchKernelGGL(finalize_kernel, dim3(16),   dim3(256), 0, stream,
                       psum, psumsq, gamma, beta, scale, shift);
    hipLaunchKernelGGL(convW_kernel,    dim3(1024), dim3(256), 0, stream,
                       W, scale, shift, b, Wbf, biasN);
    hipLaunchKernelGGL(gemm256_kernel,  dim3(512),  dim3(512), 0, stream,
                       Hbf, Wbf, biasN, out);
}

// Round 8
// 292.196 us; speedup vs baseline: 1.3110x; 1.1407x over previous
//
#include <hip/hip_runtime.h>

// ---------------------------------------------------------------------------
// Problem: h = relu(x + noise); BN1d(train, eps=0.8); z = hn @ W^T + b
// Folded form: z = h @ (scale*W)^T + (b + W @ shift),  h = relu(x+noise)
// x: [8192, 4096] f32, W: [4096, 4096] f32, out: [8192, 4096] f32
// ---------------------------------------------------------------------------

#define B_ROWS 8192
#define C_CH   4096
#define N_OUT  4096

// ---------------------- compile-time noise table --------------------------
struct alignas(16) NoiseTable { float v[C_CH]; };

constexpr NoiseTable make_noise() {
    unsigned s = 123u;
    unsigned pool[C_CH] = {};
    for (int i = 0; i < C_CH; ++i) { s = 65539u * s + 1u; pool[i] = s; }
    int nxt = C_CH - 1;
    NoiseTable t{};
    for (int i = 0; i < C_CH; ++i) {
        nxt = (int)(pool[nxt] % (unsigned)C_CH);
        t.v[i] = (float)((double)pool[nxt] * 1e-9);
        s = 65539u * s + 1u;
        pool[nxt] = s;
    }
    return t;
}

__device__ constexpr NoiseTable NOISE = make_noise();

// ---------------------- helpers -------------------------------------------
__device__ __forceinline__ unsigned short f2bf(float f) {
    unsigned u = __builtin_bit_cast(unsigned, f);
    unsigned r = (u + 0x7FFFu + ((u >> 16) & 1u)) >> 16;   // RNE
    return (unsigned short)r;
}

typedef __attribute__((ext_vector_type(8))) short bf16x8;
typedef __attribute__((ext_vector_type(4))) float f32x4;

__device__ __forceinline__ void gload16(const void* g, void* l) {
    __builtin_amdgcn_global_load_lds(
        (const __attribute__((address_space(1))) void*)g,
        (__attribute__((address_space(3))) void*)l, 16, 0, 0);
}

#define BARRIER()  do { __builtin_amdgcn_s_barrier(); asm volatile("" ::: "memory"); } while (0)
#define SCHED0()   __builtin_amdgcn_sched_barrier(0)
#define LGKM(N)    do { asm volatile("s_waitcnt lgkmcnt(" #N ")" ::: "memory"); \
                        __builtin_amdgcn_sched_barrier(0); } while (0)

// ------- 1) fused: h = relu(x+noise) -> bf16, + per-block BN partials -------
__global__ __launch_bounds__(256) void conv_h_kernel(const float* __restrict__ x,
                                                     unsigned short* __restrict__ Hbf,
                                                     float* __restrict__ psum,
                                                     float* __restrict__ psumsq) {
    const int t = threadIdx.x;
    const int b = blockIdx.x;

    float4 nv[4];
    #pragma unroll
    for (int g = 0; g < 4; ++g)
        nv[g] = *reinterpret_cast<const float4*>(&NOISE.v[g * 1024 + 4 * t]);

    float4 s[4], q[4];
    #pragma unroll
    for (int g = 0; g < 4; ++g) { s[g] = make_float4(0,0,0,0); q[g] = make_float4(0,0,0,0); }

    const int row0 = b * 16;
    for (int r = 0; r < 16; ++r) {
        const size_t rb = (size_t)(row0 + r) * C_CH;
        const float* xr = x + rb;
        #pragma unroll
        for (int g = 0; g < 4; ++g) {
            float4 v = *reinterpret_cast<const float4*>(&xr[g * 1024 + 4 * t]);
            float h0 = fmaxf(v.x + nv[g].x, 0.f);
            float h1 = fmaxf(v.y + nv[g].y, 0.f);
            float h2 = fmaxf(v.z + nv[g].z, 0.f);
            float h3 = fmaxf(v.w + nv[g].w, 0.f);
            s[g].x += h0; s[g].y += h1; s[g].z += h2; s[g].w += h3;
            q[g].x += h0*h0; q[g].y += h1*h1; q[g].z += h2*h2; q[g].w += h3*h3;
            ushort4 o;
            o.x = f2bf(h0); o.y = f2bf(h1); o.z = f2bf(h2); o.w = f2bf(h3);
            *reinterpret_cast<ushort4*>(&Hbf[rb + g * 1024 + 4 * t]) = o;
        }
    }
    #pragma unroll
    for (int g = 0; g < 4; ++g) {
        *reinterpret_cast<float4*>(&psum  [(size_t)b * C_CH + g * 1024 + 4 * t]) = s[g];
        *reinterpret_cast<float4*>(&psumsq[(size_t)b * C_CH + g * 1024 + 4 * t]) = q[g];
    }
}

// ------- 2) finalize (parallel): scale/shift per channel -------------------
// 128 blocks x 32 channels. Thread t: channel bid*32+(t&31), partial-group
// t>>5 (64 of the 512 partial rows); 32-lane-coalesced 128 B reads; LDS
// 8x32 tree reduce; 32 threads finish scale/shift. Fixed-order deterministic.
__global__ __launch_bounds__(256) void finalize_kernel(const float* __restrict__ psum,
                                                       const float* __restrict__ psumsq,
                                                       const float* __restrict__ gamma,
                                                       const float* __restrict__ beta,
                                                       float* __restrict__ scale,
                                                       float* __restrict__ shift) {
    __shared__ float ls[8][32], lq[8][32];
    const int t  = threadIdx.x;
    const int c  = blockIdx.x * 32 + (t & 31);
    const int g  = t >> 5;
    float s = 0.f, q = 0.f;
    const int bk0 = g * 64;
    for (int bk = bk0; bk < bk0 + 64; ++bk) {
        s += psum  [(size_t)bk * C_CH + c];
        q += psumsq[(size_t)bk * C_CH + c];
    }
    ls[g][t & 31] = s; lq[g][t & 31] = q;
    __syncthreads();
    if (t < 32) {
        float S = 0.f, Q = 0.f;
        #pragma unroll
        for (int g2 = 0; g2 < 8; ++g2) { S += ls[g2][t]; Q += lq[g2][t]; }
        const int ch = blockIdx.x * 32 + t;
        const float inv  = 1.f / (float)B_ROWS;
        const float mean = S * inv;
        const float var  = fmaxf(Q * inv - mean * mean, 0.f);
        const float sc   = gamma[ch] / sqrtf(var + 0.8f);
        scale[ch] = sc;
        shift[ch] = beta[ch] - mean * sc;
    }
}

// ------- 3) convW': W' = scale*W (bf16) + bias' = b + W @ shift (f32) -------
__global__ __launch_bounds__(256) void convW_kernel(const float* __restrict__ W,
                                                    const float* __restrict__ scale,
                                                    const float* __restrict__ shift,
                                                    const float* __restrict__ b,
                                                    unsigned short* __restrict__ Wbf,
                                                    float* __restrict__ biasN) {
    const int wv   = threadIdx.x >> 6;
    const int lane = threadIdx.x & 63;
    const int o    = blockIdx.x * 4 + wv;
    const float* wr = W + (size_t)o * C_CH;
    unsigned short* wo = Wbf + (size_t)o * C_CH;

    float acc = 0.f;
    #pragma unroll
    for (int s = 0; s < 16; ++s) {
        const int c = s * 256 + lane * 4;
        float4 v  = *reinterpret_cast<const float4*>(&wr[c]);
        float4 sc = *reinterpret_cast<const float4*>(&scale[c]);
        float4 sh = *reinterpret_cast<const float4*>(&shift[c]);
        ushort4 ov;
        ov.x = f2bf(v.x * sc.x); ov.y = f2bf(v.y * sc.y);
        ov.z = f2bf(v.z * sc.z); ov.w = f2bf(v.w * sc.w);
        *reinterpret_cast<ushort4*>(&wo[c]) = ov;
        acc += sh.x * v.x + sh.y * v.y + sh.z * v.z + sh.w * v.w;
    }
    #pragma unroll
    for (int off = 32; off > 0; off >>= 1)
        acc += __shfl_down(acc, off);
    if (lane == 0) biasN[o] = b[o] + acc;
}

// ---------------------- 4) GEMM 256x256x64 (R7 schedule, frozen best) ------
// LDS buffer 65536 B: A chunks A0..A3 (64 rows each) at 0/8192/16384/24576,
// B chunks at +32768. T2 swizzle slot^(row&7), source pre-swizzled.
// Stage order for t+1: ph0 {B0,B1}, ph1 {B2,B3}, ph2 {A0,A2}, ph3 {A1,A3};
// waits vmcnt(2)@barrier1, vmcnt(4)@barrier2. 2 barriers/K-tile. Fragment
// ds_reads issued in sched_barrier-ordered groups, waited with counted lgkmcnt.

template<int MH, int NH>
__device__ __forceinline__ void quad_mfma(bf16x8 (&af)[4][2], bf16x8 (&bfr)[4][2],
                                          f32x4 (&acc)[8][4]) {
    #pragma unroll
    for (int s = 0; s < 2; ++s)
        #pragma unroll
        for (int m = 0; m < 4; ++m)
            #pragma unroll
            for (int n = 0; n < 2; ++n)
                acc[MH * 4 + m][NH * 2 + n] = __builtin_amdgcn_mfma_f32_16x16x32_bf16(
                    af[m][s], bfr[NH * 2 + n][s], acc[MH * 4 + m][NH * 2 + n], 0, 0, 0);
}

template<bool STG>
__device__ __forceinline__ void tile_step(
    char* lds, const int bc, const int bn,
    const char*& pA0, const char*& pA1, const char*& pA2, const char*& pA3,
    const char*& pB0, const char*& pB1, const char*& pB2, const char*& pB3,
    const int dstw, const int aoff0, const int aoff1,
    const int boff0, const int boff1,
    f32x4 (&acc)[8][4]) {

    bf16x8 af[4][2], bfr[4][2];

    // ======== first half: Q00 + Q01 ========
    asm volatile("s_waitcnt vmcnt(2)" ::: "memory");   // B0-3,A0,A2 of t landed
    BARRIER();                        // block-wide landing + bn reuse fence
    SCHED0();
    if (STG) {
        gload16(pB0, lds + bn + 32768 + dstw);
        gload16(pB1, lds + bn + 40960 + dstw);
    }
    // group 1 (12 reads): af m0-3 both k-slots + bf n0-1
    #pragma unroll
    for (int m = 0; m < 4; ++m) {
        af[m][0] = *reinterpret_cast<const bf16x8*>(lds + bc + aoff0 + m * 2048);
        af[m][1] = *reinterpret_cast<const bf16x8*>(lds + bc + aoff1 + m * 2048);
    }
    #pragma unroll
    for (int n = 0; n < 2; ++n) {
        bfr[n][0] = *reinterpret_cast<const bf16x8*>(lds + bc + boff0 + n * 2048);
        bfr[n][1] = *reinterpret_cast<const bf16x8*>(lds + bc + boff1 + n * 2048);
    }
    SCHED0();
    // group 2 (4 reads): bf n2-3
    #pragma unroll
    for (int n = 2; n < 4; ++n) {
        bfr[n][0] = *reinterpret_cast<const bf16x8*>(lds + bc + boff0 + n * 2048);
        bfr[n][1] = *reinterpret_cast<const bf16x8*>(lds + bc + boff1 + n * 2048);
    }
    LGKM(4);                          // group 1 done; group 2 drains under Q00
    __builtin_amdgcn_s_setprio(1);
    quad_mfma<0, 0>(af, bfr, acc);
    __builtin_amdgcn_s_setprio(0);
    if (STG) {
        gload16(pB2, lds + bn + 49152 + dstw);
        gload16(pB3, lds + bn + 57344 + dstw);
    }
    LGKM(0);                          // group 2 done
    __builtin_amdgcn_s_setprio(1);
    quad_mfma<0, 1>(af, bfr, acc);
    __builtin_amdgcn_s_setprio(0);

    // ======== second half: Q11 + Q10 ========
    if (STG) asm volatile("s_waitcnt vmcnt(4)" ::: "memory");  // A1,A3 of t landed
    else     asm volatile("s_waitcnt vmcnt(0)" ::: "memory");
    BARRIER();
    SCHED0();
    if (STG) {
        gload16(pA0, lds + bn +     0 + dstw);
        gload16(pA2, lds + bn + 16384 + dstw);
    }
    // group 3 (4 reads): af[0..1] <- phys rows m4,m5
    #pragma unroll
    for (int m = 0; m < 2; ++m) {
        af[m][0] = *reinterpret_cast<const bf16x8*>(lds + bc + aoff0 + (m + 4) * 2048);
        af[m][1] = *reinterpret_cast<const bf16x8*>(lds + bc + aoff1 + (m + 4) * 2048);
    }
    SCHED0();
    // group 4 (4 reads): af[2..3] <- phys rows m6,m7
    #pragma unroll
    for (int m = 2; m < 4; ++m) {
        af[m][0] = *reinterpret_cast<const bf16x8*>(lds + bc + aoff0 + (m + 4) * 2048);
        af[m][1] = *reinterpret_cast<const bf16x8*>(lds + bc + aoff1 + (m + 4) * 2048);
    }
    LGKM(4);                          // group 3 done; group 4 drains under MFMA
    __builtin_amdgcn_s_setprio(1);
    #pragma unroll
    for (int s = 0; s < 2; ++s)
        #pragma unroll
        for (int m = 0; m < 2; ++m)
            #pragma unroll
            for (int n = 2; n < 4; ++n)
                acc[4 + m][n] = __builtin_amdgcn_mfma_f32_16x16x32_bf16(
                    af[m][s], bfr[n][s], acc[4 + m][n], 0, 0, 0);
    __builtin_amdgcn_s_setprio(0);
    if (STG) {
        gload16(pA1, lds + bn +  8192 + dstw);
        gload16(pA3, lds + bn + 24576 + dstw);
        pA0 += 128; pA1 += 128; pA2 += 128; pA3 += 128;
        pB0 += 128; pB1 += 128; pB2 += 128; pB3 += 128;
    }
    LGKM(0);                          // group 4 done
    __builtin_amdgcn_s_setprio(1);
    #pragma unroll
    for (int s = 0; s < 2; ++s)
        #pragma unroll
        for (int m = 2; m < 4; ++m)
            #pragma unroll
            for (int n = 2; n < 4; ++n)
                acc[4 + m][n] = __builtin_amdgcn_mfma_f32_16x16x32_bf16(
                    af[m][s], bfr[n][s], acc[4 + m][n], 0, 0, 0);
    // Q10: pure register
    #pragma unroll
    for (int s = 0; s < 2; ++s)
        #pragma unroll
        for (int m = 0; m < 4; ++m)
            #pragma unroll
            for (int n = 0; n < 2; ++n)
                acc[4 + m][n] = __builtin_amdgcn_mfma_f32_16x16x32_bf16(
                    af[m][s], bfr[n][s], acc[4 + m][n], 0, 0, 0);
    __builtin_amdgcn_s_setprio(0);
}

__global__ __launch_bounds__(512, 2) void gemm256_kernel(
    const unsigned short* __restrict__ A, const unsigned short* __restrict__ B,
    const float* __restrict__ bias, float* __restrict__ C) {
    constexpr int K = C_CH, N = N_OUT;
    __shared__ alignas(128) char lds[131072];

    // XCD-bijective swizzle (nwg = 512, % 8 == 0)
    const int nwg = gridDim.x;
    const int cpx = nwg >> 3;
    int wg = blockIdx.x;
    wg = (wg & 7) * cpx + (wg >> 3);
    const int nbx = N >> 8;                 // 16
    const int bx = wg % nbx, by = wg / nbx;
    const int row0 = by << 8, col0 = bx << 8;

    const int t    = threadIdx.x;
    const int lane = t & 63;
    const int wid  = t >> 6;
    const int wm   = wid >> 2;              // 0..1
    const int wn   = wid & 3;               // 0..3
    const int l15  = lane & 15;
    const int lh   = lane >> 4;             // 0..3

    // staging source (pre-swizzled slot) and wave-uniform LDS dest
    const int sslot = (lane & 7) ^ (lane >> 3);
    const int dstw  = wid << 10;            // wid * 1024

    const char* pA0 = (const char*)A +
        ((size_t)(row0 + wid * 8 + (lane >> 3)) * K) * 2 + sslot * 16;
    const char* pA1 = pA0 + 1 * 64 * K * 2;
    const char* pA2 = pA0 + 2 * 64 * K * 2;
    const char* pA3 = pA0 + 3 * 64 * K * 2;
    const char* pB0 = (const char*)B +
        ((size_t)(col0 + wid * 8 + (lane >> 3)) * K) * 2 + sslot * 16;
    const char* pB1 = pB0 + 1 * 64 * K * 2;
    const char* pB2 = pB0 + 2 * 64 * K * 2;
    const char* pB3 = pB0 + 3 * 64 * K * 2;

    // fragment read offsets (T2 swizzle: slot ^ (row&7), row&7 == l15&7)
    const int x7 = l15 & 7;
    const int aoff0 = wm * 16384 + l15 * 128 + ((lh     ) ^ x7) * 16;
    const int aoff1 = wm * 16384 + l15 * 128 + ((lh +  4) ^ x7) * 16;
    const int boff0 = 32768 + wn * 8192 + l15 * 128 + ((lh    ) ^ x7) * 16;
    const int boff1 = 32768 + wn * 8192 + l15 * 128 + ((lh + 4) ^ x7) * 16;

    f32x4 acc[8][4];
    #pragma unroll
    for (int m = 0; m < 8; ++m)
        #pragma unroll
        for (int n = 0; n < 4; ++n)
            acc[m][n] = (f32x4){0.f, 0.f, 0.f, 0.f};

    // prologue: stage tile 0 into buf0 in vmcnt-matched order
    // (B0,B1,B2,B3,A0,A2 = oldest 6; A1,A3 = newest 2)
    gload16(pB0, lds + 32768 + dstw);
    gload16(pB1, lds + 40960 + dstw);
    gload16(pB2, lds + 49152 + dstw);
    gload16(pB3, lds + 57344 + dstw);
    gload16(pA0, lds +     0 + dstw);
    gload16(pA2, lds + 16384 + dstw);
    gload16(pA1, lds +  8192 + dstw);
    gload16(pA3, lds + 24576 + dstw);
    pA0 += 128; pA1 += 128; pA2 += 128; pA3 += 128;
    pB0 += 128; pB1 += 128; pB2 += 128; pB3 += 128;

    // 64 K-tiles: 31 double iterations + staged tile + tail tile
    #pragma unroll 1
    for (int it = 0; it < 31; ++it) {
        tile_step<true >(lds,     0, 65536, pA0, pA1, pA2, pA3, pB0, pB1, pB2, pB3,
                         dstw, aoff0, aoff1, boff0, boff1, acc);
        tile_step<true >(lds, 65536,     0, pA0, pA1, pA2, pA3, pB0, pB1, pB2, pB3,
                         dstw, aoff0, aoff1, boff0, boff1, acc);
    }
    tile_step<true >(lds,     0, 65536, pA0, pA1, pA2, pA3, pB0, pB1, pB2, pB3,
                     dstw, aoff0, aoff1, boff0, boff1, acc);
    tile_step<false>(lds, 65536,     0, pA0, pA1, pA2, pA3, pB0, pB1, pB2, pB3,
                     dstw, aoff0, aoff1, boff0, boff1, acc);

    // epilogue: C[row][col] = acc + bias[col]
    const int crow0 = row0 + wm * 128 + lh * 4;
    const int ccol0 = col0 + wn * 64 + l15;
    #pragma unroll
    for (int n = 0; n < 4; ++n) {
        const float bv = bias[ccol0 + n * 16];
        #pragma unroll
        for (int m = 0; m < 8; ++m) {
            const size_t base = (size_t)(crow0 + m * 16) * N + (ccol0 + n * 16);
            #pragma unroll
            for (int j = 0; j < 4; ++j)
                C[base + (size_t)j * N] = acc[m][n][j] + bv;
        }
    }
}

// ---------------------- launch --------------------------------------------
extern "C" void kernel_launch(void* const* d_in, const int* in_sizes, int n_in,
                              void* d_out, int out_size, void* d_ws, size_t ws_size,
                              hipStream_t stream) {
    const float* x     = (const float*)d_in[0];
    const float* gamma = (const float*)d_in[1];
    const float* beta  = (const float*)d_in[2];
    const float* W     = (const float*)d_in[3];
    const float* b     = (const float*)d_in[4];
    float* out = (float*)d_out;

    char* ws = (char*)d_ws;
    unsigned short* Hbf = (unsigned short*)(ws);                       // 64 MiB
    unsigned short* Wbf = (unsigned short*)(ws + 67108864);            // 32 MiB
    float* psum   = (float*)(ws + 100663296);                          // 8 MiB
    float* psumsq = (float*)(ws + 109051904);                          // 8 MiB
    float* scale  = (float*)(ws + 117440512);                          // 16 KiB
    float* shift  = (float*)(ws + 117440512 + 16384);                  // 16 KiB
    float* biasN  = (float*)(ws + 117440512 + 32768);                  // 16 KiB

    hipLaunchKernelGGL(conv_h_kernel,   dim3(512),  dim3(256), 0, stream,
                       x, Hbf, psum, psumsq);
    hipLaunchKernelGGL(finalize_kernel, dim3(128),  dim3(256), 0, stream,
                       psum, psumsq, gamma, beta, scale, shift);
    hipLaunchKernelGGL(convW_kernel,    dim3(1024), dim3(256), 0, stream,
                       W, scale, shift, b, Wbf, biasN);
    hipLaunchKernelGGL(gemm256_kernel,  dim3(512),  dim3(512), 0, stream,
                       Hbf, Wbf, biasN, out);
}